// Round 2
// baseline (838.299 us; speedup 1.0000x reference)
//
#include <hip/hip_runtime.h>

#define EPSF 1e-7f

constexpr int Bn = 4, Cn = 64, Kn = 19;
constexpr int HWn = 512 * 512;
constexpr int CHUNKS = 64;                 // chunks per image
constexpr int PIXPERBLK = HWn / CHUNKS;    // 4096 pixels per block
constexpr int THREADS = 1024;
constexpr int RREP = 4;                    // LDS accumulator replicas
constexpr int RSTRIDE = Cn * Kn + 8;       // 1224: replica region stride (bank spread)
constexpr int SQOFF = RREP * RSTRIDE;      // 4896: offset of sumsq region
constexpr int PARTSZ = 2 * Cn * Kn;        // 2432 floats per block partial

// ---------------- Kernel 1: per-(b,k,c) sum / sumsq / count ----------------
__global__ __launch_bounds__(THREADS) void k_stats(
    const float* __restrict__ x, const int* __restrict__ gt,
    float* __restrict__ part, int* __restrict__ gcnt)
{
    __shared__ float acc[2 * SQOFF];          // [sum | sq], each RREP*RSTRIDE
    __shared__ int   scnt[RREP * Kn];
    const int tid = threadIdx.x;

    for (int i = tid; i < 2 * SQOFF; i += THREADS) acc[i] = 0.f;
    if (tid < RREP * Kn) scnt[tid] = 0;
    __syncthreads();

    const int b     = blockIdx.x >> 6;
    const int chunk = blockIdx.x & 63;
    const int p0    = chunk * PIXPERBLK + tid * 4;

    const int4 L = *reinterpret_cast<const int4*>(gt + (size_t)b * HWn + p0);
    const int l0 = min(max(L.x, 0), Kn - 1);
    const int l1 = min(max(L.y, 0), Kn - 1);
    const int l2 = min(max(L.z, 0), Kn - 1);
    const int l3 = min(max(L.w, 0), Kn - 1);

    const int r  = (tid & 3);
    const int a0 = r * RSTRIDE + l0;
    const int a1 = r * RSTRIDE + l1;
    const int a2 = r * RSTRIDE + l2;
    const int a3 = r * RSTRIDE + l3;

    atomicAdd(&scnt[r * Kn + l0], 1);
    atomicAdd(&scnt[r * Kn + l1], 1);
    atomicAdd(&scnt[r * Kn + l2], 1);
    atomicAdd(&scnt[r * Kn + l3], 1);

    const float* xp = x + (size_t)b * Cn * HWn + p0;
    #pragma unroll 16
    for (int c = 0; c < Cn; ++c) {
        const float4 v = *reinterpret_cast<const float4*>(xp + (size_t)c * HWn);
        const int co = c * Kn;
        atomicAdd(&acc[a0 + co], v.x);  atomicAdd(&acc[a0 + co + SQOFF], v.x * v.x);
        atomicAdd(&acc[a1 + co], v.y);  atomicAdd(&acc[a1 + co + SQOFF], v.y * v.y);
        atomicAdd(&acc[a2 + co], v.z);  atomicAdd(&acc[a2 + co + SQOFF], v.z * v.z);
        atomicAdd(&acc[a3 + co], v.w);  atomicAdd(&acc[a3 + co + SQOFF], v.w * v.w);
    }
    __syncthreads();

    // flush: reduce replicas -> per-block partial in workspace (deterministic 2nd stage)
    float* pb = part + (size_t)blockIdx.x * PARTSZ;
    for (int i = tid; i < Cn * Kn; i += THREADS) {          // i = c*19 + k
        float s = acc[i] + acc[RSTRIDE + i] + acc[2 * RSTRIDE + i] + acc[3 * RSTRIDE + i];
        float q = acc[SQOFF + i] + acc[SQOFF + RSTRIDE + i]
                + acc[SQOFF + 2 * RSTRIDE + i] + acc[SQOFF + 3 * RSTRIDE + i];
        pb[i] = s;
        pb[Cn * Kn + i] = q;
    }
    if (tid < Kn) {
        int t = scnt[tid] + scnt[Kn + tid] + scnt[2 * Kn + tid] + scnt[3 * Kn + tid];
        atomicAdd(&gcnt[b * Kn + tid], t);
    }
}

// ---------------- Kernel 2: mean/std + mixing weights -> A,B tables ----------------
__global__ __launch_bounds__(256) void k_tables(
    const float* __restrict__ part, const int* __restrict__ gcnt,
    const float* __restrict__ aug, float* __restrict__ tabA, float* __restrict__ tabB)
{
    __shared__ float mean_s[Kn * Cn];   // [k*64 + c]
    __shared__ float std_s [Kn * Cn];
    __shared__ float wrow  [Kn * Kn];   // [t*19 + k]
    __shared__ float wsum  [Kn];
    __shared__ float validf[Kn], cntf[Kn];

    const int b = blockIdx.x, tid = threadIdx.x;

    if (tid < Kn) {
        const int cc = gcnt[b * Kn + tid];
        validf[tid] = (cc > 0) ? 1.f : 0.f;
        cntf[tid]   = (cc > 0) ? (float)cc : 1.f;
    }
    __syncthreads();

    for (int i = tid; i < Cn * Kn; i += 256) {              // i = c*19 + k
        float s = 0.f, q = 0.f;
        const float* pp = part + (size_t)b * CHUNKS * PARTSZ + i;
        for (int blk = 0; blk < CHUNKS; ++blk) {
            s += pp[(size_t)blk * PARTSZ];
            q += pp[(size_t)blk * PARTSZ + Cn * Kn];
        }
        const int c = i / Kn, k = i - c * Kn;
        const float cs  = cntf[k];
        const float m   = s / cs;
        const float var = fmaxf(q / cs - m * m, 0.f);
        mean_s[k * Cn + c] = m;
        std_s [k * Cn + c] = sqrtf(var) + EPSF;
    }
    // FIX (R1): Kn*Kn = 361 > blockDim (256) — must be a strided loop, the
    // old `if (tid < Kn*Kn)` left wrow[256..360] uninitialized (absmax 1.8e9).
    for (int i = tid; i < Kn * Kn; i += 256) {
        const int t = i / Kn, k = i - t * Kn;
        wrow[i] = aug[((size_t)b * Kn + t) * Kn + k] * validf[k];
    }
    __syncthreads();
    if (tid < Kn) {
        float s = 0.f;
        for (int k = 0; k < Kn; ++k) s += wrow[tid * Kn + k];
        wsum[tid] = fmaxf(s, EPSF);
    }
    __syncthreads();
    for (int i = tid; i < Kn * Cn; i += 256) {              // i = t*64 + c
        const int t = i >> 6, c = i & 63;
        const float inv = 1.f / wsum[t];
        float mm = 0.f, ms = 0.f;
        for (int k = 0; k < Kn; ++k) {
            const float wk = wrow[t * Kn + k] * inv;
            mm += wk * mean_s[k * Cn + c];
            ms += wk * std_s [k * Cn + c];
        }
        const float A  = ms / std_s[t * Cn + c];
        const float Bv = mm - mean_s[t * Cn + c] * A;
        tabA[(size_t)b * Cn * Kn + c * Kn + t] = A;   // [b][c][k] layout for K3 LDS
        tabB[(size_t)b * Cn * Kn + c * Kn + t] = Bv;
    }
}

// ---------------- Kernel 3: out = x*A[gt] + B[gt] ----------------
__global__ __launch_bounds__(THREADS) void k_apply(
    const float* __restrict__ x, const int* __restrict__ gt,
    const float* __restrict__ tabA, const float* __restrict__ tabB,
    float* __restrict__ out)
{
    __shared__ float As[Cn * Kn], Bs[Cn * Kn];   // [c*19 + k]
    const int tid   = threadIdx.x;
    const int b     = blockIdx.x >> 6;
    const int chunk = blockIdx.x & 63;

    for (int i = tid; i < Cn * Kn; i += THREADS) {
        As[i] = tabA[(size_t)b * Cn * Kn + i];
        Bs[i] = tabB[(size_t)b * Cn * Kn + i];
    }
    __syncthreads();

    const int p0 = chunk * PIXPERBLK + tid * 4;
    const int4 L = *reinterpret_cast<const int4*>(gt + (size_t)b * HWn + p0);
    const int l0 = min(max(L.x, 0), Kn - 1);
    const int l1 = min(max(L.y, 0), Kn - 1);
    const int l2 = min(max(L.z, 0), Kn - 1);
    const int l3 = min(max(L.w, 0), Kn - 1);

    const float* xp = x   + (size_t)b * Cn * HWn + p0;
    float*       op = out + (size_t)b * Cn * HWn + p0;

    #pragma unroll 16
    for (int c = 0; c < Cn; ++c) {
        const float4 v = *reinterpret_cast<const float4*>(xp + (size_t)c * HWn);
        const int co = c * Kn;
        float4 o;
        o.x = v.x * As[co + l0] + Bs[co + l0];
        o.y = v.y * As[co + l1] + Bs[co + l1];
        o.z = v.z * As[co + l2] + Bs[co + l2];
        o.w = v.w * As[co + l3] + Bs[co + l3];
        *reinterpret_cast<float4*>(op + (size_t)c * HWn) = o;
    }
}

extern "C" void kernel_launch(void* const* d_in, const int* in_sizes, int n_in,
                              void* d_out, int out_size, void* d_ws, size_t ws_size,
                              hipStream_t stream) {
    const float* x   = (const float*)d_in[0];
    const int*   gt  = (const int*)d_in[1];
    const float* aug = (const float*)d_in[2];
    float* out = (float*)d_out;

    // workspace layout (floats): partials | gcnt(int,128) | tabA | tabB
    float* part = (float*)d_ws;                                   // 256*2432
    int*   gcnt = (int*)(part + (size_t)Bn * CHUNKS * PARTSZ);    // 76 used, 128 reserved
    float* tabA = (float*)(gcnt + 128);
    float* tabB = tabA + (size_t)Bn * Cn * Kn;

    hipMemsetAsync(gcnt, 0, 128 * sizeof(int), stream);
    k_stats <<<dim3(Bn * CHUNKS), dim3(THREADS), 0, stream>>>(x, gt, part, gcnt);
    k_tables<<<dim3(Bn),          dim3(256),     0, stream>>>(part, gcnt, aug, tabA, tabB);
    k_apply <<<dim3(Bn * CHUNKS), dim3(THREADS), 0, stream>>>(x, gt, tabA, tabB, out);
}